// Round 3
// baseline (432.713 us; speedup 1.0000x reference)
//
#include <hip/hip_runtime.h>
#include <math.h>

// ---------------------------------------------------------------------------
// FusionMoE R3: AITER-style K-loops. A-fragments direct global->VGPR (no
// barrier dependency); B (weights, L2-hot) via global_load_lds into a ring-3
// LDS buffer with ONE manual s_waitcnt vmcnt(8)+s_barrier per kit (prefetch
// depth 2 stays in flight across the barrier). BK=32. Combine uses ring-2
// with standard syncthreads dbuf.
// ---------------------------------------------------------------------------

typedef unsigned short u16;
typedef unsigned int u32;
typedef __attribute__((ext_vector_type(8))) short bf16x8;
typedef __attribute__((ext_vector_type(4))) float f32x4;

__device__ __forceinline__ float bf2f(u16 u) {
    union { u32 i; float f; } v; v.i = ((u32)u) << 16; return v.f;
}
__device__ __forceinline__ u16 f2bf(float f) {  // RNE
    union { float f; u32 i; } v; v.f = f;
    u32 x = v.i;
    return (u16)((x + 0x7fffu + ((x >> 16) & 1u)) >> 16);
}
__device__ __forceinline__ float gelu_exact(float v) {
    return 0.5f * v * (1.0f + erff(v * 0.70710678118654752f));
}

typedef __attribute__((address_space(1))) void GV;
typedef __attribute__((address_space(3))) void SV;
__device__ __forceinline__ void gldlds(const void* g, void* l) {
    __builtin_amdgcn_global_load_lds((GV*)g, (SV*)l, 16, 0, 0);
}
// pack two f32 (bit-truncate) into one u32 of two bf16
__device__ __forceinline__ u32 pk2(u32 f0, u32 f1) {
    return __builtin_amdgcn_perm(f1, f0, 0x07060302);
}

// one barrier per kit; allow 8 newer vmem ops (the depth-1/2 prefetches)
#define FWAIT() asm volatile("s_waitcnt vmcnt(8) lgkmcnt(0)\n\ts_barrier" ::: "memory")

// ---------------------------------------------------------------------------
// K0: prep — weight transposes to bf16 + lbacc zero
// ---------------------------------------------------------------------------
#define SEG_WF  409600
#define SEG_W1  524288
#define SEG_W2  524288
#define SEG_W3  262144
#define PREP_ITEMS (SEG_WF + SEG_W1 + SEG_W2 + SEG_W3 + 8)

__global__ __launch_bounds__(256) void prep_kernel(
    const float* __restrict__ Wf, const float* __restrict__ W1, const float* __restrict__ W2,
    const float* __restrict__ W3,
    u16* __restrict__ wft, u16* __restrict__ w1t, u16* __restrict__ w2t, u16* __restrict__ w3t,
    float* __restrict__ lbacc) {
    int idx = blockIdx.x * 256 + threadIdx.x;
    if (idx < SEG_WF) {  // WfT[n<256][k<1600] = Wf[k][n]
        int n = idx / 1600, k = idx % 1600;
        wft[idx] = f2bf(Wf[(size_t)k * 256 + n]);
        return;
    }
    idx -= SEG_WF;
    if (idx < SEG_W1) {  // W1T[e][n<512][k<256] = W1[e][k][n]
        int e = idx >> 17, r = idx & 131071;
        int n = r >> 8, k = r & 255;
        w1t[idx] = f2bf(W1[(size_t)e * 131072 + (size_t)k * 512 + n]);
        return;
    }
    idx -= SEG_W1;
    if (idx < SEG_W2) {  // W2T[e][n<256][k<512] = W2[e][k][n]
        int e = idx >> 17, r = idx & 131071;
        int n = r >> 9, k = r & 511;
        w2t[idx] = f2bf(W2[(size_t)e * 131072 + (size_t)k * 256 + n]);
        return;
    }
    idx -= SEG_W2;
    if (idx < SEG_W3) {  // W3T[e][n<256][k<256] = W3[e][k][n]
        int e = idx >> 16, r = idx & 65535;
        int n = r >> 8, k = r & 255;
        w3t[idx] = f2bf(W3[(size_t)e * 65536 + (size_t)k * 256 + n]);
        return;
    }
    idx -= SEG_W3;
    if (idx < 8) lbacc[idx] = 0.0f;
}

// ---------------------------------------------------------------------------
// K1: fusion — 32x256 tile, 50 kits of BK=32 over concat(vis,lang,state).
// A fp32 direct-to-VGPR (perm-packed), B ring-3 LDS. Epilogue: LN+GELU+gate.
// ---------------------------------------------------------------------------
__global__ __launch_bounds__(256) void fusion_kernel(
    const float* __restrict__ vis, const float* __restrict__ lang, const float* __restrict__ state,
    const u16* __restrict__ BT, const float* __restrict__ bfv_, const float* __restrict__ gf,
    const float* __restrict__ bfln, const float* __restrict__ Wg,
    u16* __restrict__ xbf, float* __restrict__ wr, float* __restrict__ lbacc) {
    __shared__ __align__(16) u16 Bs[3][8192];   // 3 x 16KB ring (256n x 32k)
    int tid = threadIdx.x;
    int w = tid >> 6, lane = tid & 63, quad = lane >> 4, l16 = lane & 15;
    int m0 = blockIdx.x * 32;
    f32x4 acc[2][4] = {};
    uint4 ar[3][2][2];

    auto stage = [&](int kk, int slot) {
#pragma unroll
        for (int i = 0; i < 4; ++i) {
            int s = i * 256 + tid;
            int n = s >> 2, c = s & 3;
            gldlds(BT + (size_t)n * 1600 + kk * 32 + ((c ^ (n & 3)) << 3), &Bs[slot][s * 8]);
        }
    };
    auto loadA = [&](int kk, uint4 a[2][2]) {
        const float* base; int ld;
        if (kk < 24)      { base = vis + kk * 32;          ld = 768; }
        else if (kk < 48) { base = lang + (kk - 24) * 32;  ld = 768; }
        else              { base = state + (kk - 48) * 32; ld = 64; }
#pragma unroll
        for (int mt = 0; mt < 2; ++mt) {
            int row = m0 + mt * 16 + l16;
            const float* p = base + (size_t)row * ld + quad * 8;
            a[mt][0] = *(const uint4*)p;
            a[mt][1] = *(const uint4*)(p + 4);
        }
    };
    auto comp = [&](const uint4 a[2][2], int slot) {
        bf16x8 af[2];
#pragma unroll
        for (int mt = 0; mt < 2; ++mt) {
            union { u32 u[4]; bf16x8 v; } pk;
            pk.u[0] = pk2(a[mt][0].x, a[mt][0].y); pk.u[1] = pk2(a[mt][0].z, a[mt][0].w);
            pk.u[2] = pk2(a[mt][1].x, a[mt][1].y); pk.u[3] = pk2(a[mt][1].z, a[mt][1].w);
            af[mt] = pk.v;
        }
#pragma unroll
        for (int nt = 0; nt < 4; ++nt) {
            int n = w * 64 + nt * 16 + l16;
            bf16x8 b = *(const bf16x8*)(&Bs[slot][n * 32 + ((quad ^ (n & 3)) << 3)]);
#pragma unroll
            for (int mt = 0; mt < 2; ++mt)
                acc[mt][nt] = __builtin_amdgcn_mfma_f32_16x16x32_bf16(af[mt], b, acc[mt][nt], 0, 0, 0);
        }
    };

    stage(0, 0); loadA(0, ar[0]);
    stage(1, 1); loadA(1, ar[1]);
    for (int kb = 0; kb < 51; kb += 3) {
#pragma unroll
        for (int j = 0; j < 3; ++j) {
            int k = kb + j;
            FWAIT();
            int kk = (k + 2 <= 49) ? (k + 2) : 49;
            stage(kk, (j + 2) % 3);
            loadA(kk, ar[(j + 2) % 3]);
            if (k < 50) comp(ar[j], j);
        }
    }
    __syncthreads();   // drain tail stages before aliasing LDS as scratch

    // ---- epilogue: bias, LN, GELU, xbf store, fused gate (R2-verified) ----
    u32* SC = (u32*)(&Bs[0][0]);
    float2* red  = (float2*)SC;            // 128 float2
    float*  muv  = (float*)(SC + 256);     // 32
    float*  rsv  = (float*)(SC + 288);     // 32
    float*  gred = (float*)(SC + 512);     // 512
    float*  sacc = (float*)(SC + 1024);    // 8

    float bv[4], gvv[4], blv[4]; float4 wgv[4];
#pragma unroll
    for (int nt = 0; nt < 4; ++nt) {
        int col = w * 64 + nt * 16 + l16;
        bv[nt] = bfv_[col]; gvv[nt] = gf[col]; blv[nt] = bfln[col];
        wgv[nt] = *(const float4*)(Wg + col * 4);
    }
    if (tid < 8) sacc[tid] = 0.f;
#pragma unroll
    for (int mt = 0; mt < 2; ++mt)
#pragma unroll
        for (int r = 0; r < 4; ++r) {
            float ss = 0.f, qq = 0.f;
#pragma unroll
            for (int nt = 0; nt < 4; ++nt) {
                float v = acc[mt][nt][r] + bv[nt];
                acc[mt][nt][r] = v;
                ss += v; qq += v * v;
            }
#pragma unroll
            for (int d = 1; d < 16; d <<= 1) { ss += __shfl_xor(ss, d); qq += __shfl_xor(qq, d); }
            if (l16 == 0) red[w * 32 + mt * 16 + quad * 4 + r] = make_float2(ss, qq);
        }
    __syncthreads();
    if (tid < 32) {
        float ss = 0.f, qq = 0.f;
#pragma unroll
        for (int ww = 0; ww < 4; ++ww) { float2 t = red[ww * 32 + tid]; ss += t.x; qq += t.y; }
        float mu = ss * (1.f / 256.f);
        float var = qq * (1.f / 256.f) - mu * mu;
        muv[tid] = mu;
        rsv[tid] = 1.f / sqrtf(var + 1e-5f);
    }
    __syncthreads();
#pragma unroll
    for (int mt = 0; mt < 2; ++mt)
#pragma unroll
        for (int r = 0; r < 4; ++r) {
            int rl = mt * 16 + quad * 4 + r;
            float mu = muv[rl], rs = rsv[rl];
#pragma unroll
            for (int nt = 0; nt < 4; ++nt) {
                int col = w * 64 + nt * 16 + l16;
                float t = (acc[mt][nt][r] - mu) * rs * gvv[nt] + blv[nt];
                float g = gelu_exact(t);
                acc[mt][nt][r] = g;
                xbf[(size_t)(m0 + rl) * 256 + col] = f2bf(g);
            }
        }
#pragma unroll
    for (int mt = 0; mt < 2; ++mt)
#pragma unroll
        for (int r = 0; r < 4; ++r) {
            int rl = mt * 16 + quad * 4 + r;
            float p0 = 0.f, p1 = 0.f, p2 = 0.f, p3 = 0.f;
#pragma unroll
            for (int nt = 0; nt < 4; ++nt) {
                float g = acc[mt][nt][r];
                p0 += g * wgv[nt].x; p1 += g * wgv[nt].y;
                p2 += g * wgv[nt].z; p3 += g * wgv[nt].w;
            }
#pragma unroll
            for (int d = 1; d < 16; d <<= 1) {
                p0 += __shfl_xor(p0, d); p1 += __shfl_xor(p1, d);
                p2 += __shfl_xor(p2, d); p3 += __shfl_xor(p3, d);
            }
            if (l16 == 0) {
                float* gp = gred + w * 128 + rl * 4;
                gp[0] = p0; gp[1] = p1; gp[2] = p2; gp[3] = p3;
            }
        }
    __syncthreads();
    if (tid < 32) {
        int row = tid;
        float lg[4];
#pragma unroll
        for (int e = 0; e < 4; ++e)
            lg[e] = gred[row * 4 + e] + gred[128 + row * 4 + e] +
                    gred[256 + row * 4 + e] + gred[384 + row * 4 + e];
        float mx = fmaxf(fmaxf(lg[0], lg[1]), fmaxf(lg[2], lg[3]));
        float ex[4]; float Z = 0.f;
#pragma unroll
        for (int e = 0; e < 4; ++e) { ex[e] = expf(lg[e] - mx); Z += ex[e]; }
        int i0 = 0; float v0 = lg[0];
#pragma unroll
        for (int e = 1; e < 4; ++e) if (lg[e] > v0) { v0 = lg[e]; i0 = e; }
        int i1 = -1; float v1 = -1e30f;
#pragma unroll
        for (int e = 0; e < 4; ++e) if (e != i0 && lg[e] > v1) { v1 = lg[e]; i1 = e; }
        float t = expf(v1 - v0);
        float wA = 1.f / (1.f + t), wB = t / (1.f + t);
        float w4[4] = {0.f, 0.f, 0.f, 0.f};
        w4[i0] = wA; w4[i1] = wB;
#pragma unroll
        for (int e = 0; e < 4; ++e) wr[(size_t)(m0 + row) * 4 + e] = w4[e];
#pragma unroll
        for (int e = 0; e < 4; ++e) atomicAdd(&sacc[e], ex[e] / Z);
        atomicAdd(&sacc[4 + i0], 1.f);
        atomicAdd(&sacc[4 + i1], 1.f);
    }
    __syncthreads();
    if (tid < 8) atomicAdd(lbacc + tid, sacc[tid]);
}

// ---------------------------------------------------------------------------
// K2: expert GEMM (64x256 tile) + bias + GELU. A bf16 direct-to-VGPR,
// B ring-3 LDS, BK=32. Template: KR real kits, KITS padded to multiple of 3.
// ---------------------------------------------------------------------------
template<int KR, int KITS>
__global__ __launch_bounds__(256) void expert_kernel(
    const u16* __restrict__ A, int lda, long aE,
    const u16* __restrict__ BT, int ldb, long bE,
    const float* __restrict__ bias, int biasE,
    u16* __restrict__ outp, int ldo, long oE) {
    __shared__ __align__(16) u16 Bs[3][8192];
    int tid = threadIdx.x;
    int w = tid >> 6, lane = tid & 63, quad = lane >> 4, l16 = lane & 15;
    int m0 = blockIdx.x * 64;
    int n0 = blockIdx.y * 256;
    int e = blockIdx.z;
    const u16* Ag = A + (size_t)e * aE;
    const u16* Bg = BT + (size_t)e * bE + (size_t)n0 * ldb;
    f32x4 acc[4][4] = {};
    uint4 ar[3][4];

    auto stage = [&](int kk, int slot) {
#pragma unroll
        for (int i = 0; i < 4; ++i) {
            int s = i * 256 + tid;
            int n = s >> 2, c = s & 3;
            gldlds(Bg + (size_t)n * ldb + kk * 32 + ((c ^ (n & 3)) << 3), &Bs[slot][s * 8]);
        }
    };
    auto loadA = [&](int kk, uint4 a[4]) {
#pragma unroll
        for (int mt = 0; mt < 4; ++mt) {
            int row = m0 + mt * 16 + l16;
            a[mt] = *(const uint4*)(Ag + (size_t)row * lda + kk * 32 + quad * 8);
        }
    };
    auto comp = [&](const uint4 a[4], int slot) {
#pragma unroll
        for (int nt = 0; nt < 4; ++nt) {
            int n = w * 64 + nt * 16 + l16;
            bf16x8 b = *(const bf16x8*)(&Bs[slot][n * 32 + ((quad ^ (n & 3)) << 3)]);
#pragma unroll
            for (int mt = 0; mt < 4; ++mt) {
                union { uint4 u; bf16x8 v; } av; av.u = a[mt];
                acc[mt][nt] = __builtin_amdgcn_mfma_f32_16x16x32_bf16(av.v, b, acc[mt][nt], 0, 0, 0);
            }
        }
    };

    stage(0, 0); loadA(0, ar[0]);
    stage(1, 1); loadA(1, ar[1]);
    for (int kb = 0; kb < KITS; kb += 3) {
#pragma unroll
        for (int j = 0; j < 3; ++j) {
            int k = kb + j;
            FWAIT();
            int kk = (k + 2 <= KR - 1) ? (k + 2) : (KR - 1);
            stage(kk, (j + 2) % 3);
            loadA(kk, ar[(j + 2) % 3]);
            if (k < KR) comp(ar[j], j);
        }
    }
    __syncthreads();

#pragma unroll
    for (int nt = 0; nt < 4; ++nt) {
        int col = n0 + w * 64 + nt * 16 + l16;
        float bvv = bias[e * biasE + col];
#pragma unroll
        for (int mt = 0; mt < 4; ++mt)
#pragma unroll
            for (int r = 0; r < 4; ++r) {
                int row = m0 + mt * 16 + quad * 4 + r;
                outp[(size_t)e * oE + (size_t)row * ldo + col] = f2bf(gelu_exact(acc[mt][nt][r] + bvv));
            }
    }
}

// ---------------------------------------------------------------------------
// K3: combine — 32-row tiles, loop e: h2@W3 + b3 + x -> LN -> *eg+eb,
// out += w[row][e]*y. A direct-to-VGPR, B ring-2 LDS (syncthreads dbuf).
// ---------------------------------------------------------------------------
__global__ __launch_bounds__(256) void combine_kernel(
    const u16* __restrict__ h2, const u16* __restrict__ W3T,
    const float* __restrict__ b3, const float* __restrict__ eg, const float* __restrict__ eb,
    const u16* __restrict__ xbf, const float* __restrict__ wr,
    const float* __restrict__ lbacc, float* __restrict__ outp) {
    __shared__ __align__(16) u16 Bs[2][8192];   // 2 x 16KB ring
    __shared__ __align__(16) u16 xs[8192];      // 32 x 256 bf16
    __shared__ float wl[128];
    __shared__ float2 credv[128];
    __shared__ float cmu[32], crs[32];
    int tid = threadIdx.x;
    int w = tid >> 6, lane = tid & 63, quad = lane >> 4, l16 = lane & 15;
    int m0 = blockIdx.x * 32;
    if (blockIdx.x == 0 && tid == 0) {          // lb_loss (lbacc complete)
        float lb = 0.f;
#pragma unroll
        for (int e = 0; e < 4; ++e)
            lb += (lbacc[4 + e] / 32768.f) * (lbacc[e] / 16384.f);
        outp[4194304] = 4.f * lb;
    }
#pragma unroll
    for (int i = 0; i < 4; ++i) {
        int s = i * 256 + tid;
        *(uint4*)(xs + s * 8) = *(const uint4*)(xbf + (size_t)m0 * 256 + s * 8);
    }
    if (tid < 128) wl[tid] = wr[(size_t)m0 * 4 + tid];

    f32x4 oacc[2][4] = {};
#pragma unroll 1
    for (int e = 0; e < 4; ++e) {
        const u16* Ag = h2 + ((size_t)e * 16384 + m0) * 256;
        const u16* Bg = W3T + (size_t)e * 65536;
        f32x4 acc[2][4] = {};
        uint4 ar[2][2];

        auto stage = [&](int kk, int slot) {
#pragma unroll
            for (int i = 0; i < 4; ++i) {
                int s = i * 256 + tid;
                int n = s >> 2, c = s & 3;
                gldlds(Bg + (size_t)n * 256 + kk * 32 + ((c ^ (n & 3)) << 3), &Bs[slot][s * 8]);
            }
        };
        auto loadA = [&](int kk, uint4 a[2]) {
#pragma unroll
            for (int mt = 0; mt < 2; ++mt) {
                int row = m0 + mt * 16 + l16;
                a[mt] = *(const uint4*)(Ag + (size_t)row * 256 + kk * 32 + quad * 8);
            }
        };

        stage(0, 0); loadA(0, ar[0]);
#pragma unroll
        for (int k = 0; k < 8; ++k) {
            __syncthreads();
            if (k + 1 < 8) { stage(k + 1, (k + 1) & 1); loadA(k + 1, ar[(k + 1) & 1]); }
#pragma unroll
            for (int nt = 0; nt < 4; ++nt) {
                int n = w * 64 + nt * 16 + l16;
                bf16x8 b = *(const bf16x8*)(&Bs[k & 1][n * 32 + ((quad ^ (n & 3)) << 3)]);
#pragma unroll
                for (int mt = 0; mt < 2; ++mt) {
                    union { uint4 u; bf16x8 v; } av; av.u = ar[k & 1][mt];
                    acc[mt][nt] = __builtin_amdgcn_mfma_f32_16x16x32_bf16(av.v, b, acc[mt][nt], 0, 0, 0);
                }
            }
        }
        __syncthreads();

        float b3v[4], egv[4], ebv[4];
#pragma unroll
        for (int nt = 0; nt < 4; ++nt) {
            int col = w * 64 + nt * 16 + l16;
            b3v[nt] = b3[e * 256 + col]; egv[nt] = eg[e * 256 + col]; ebv[nt] = eb[e * 256 + col];
        }
#pragma unroll
        for (int mt = 0; mt < 2; ++mt)
#pragma unroll
            for (int r = 0; r < 4; ++r) {
                int rl = mt * 16 + quad * 4 + r;
                float ss = 0.f, qq = 0.f;
#pragma unroll
                for (int nt = 0; nt < 4; ++nt) {
                    int col = w * 64 + nt * 16 + l16;
                    float v = acc[mt][nt][r] + b3v[nt] + bf2f(xs[rl * 256 + col]);
                    acc[mt][nt][r] = v;
                    ss += v; qq += v * v;
                }
#pragma unroll
                for (int d = 1; d < 16; d <<= 1) { ss += __shfl_xor(ss, d); qq += __shfl_xor(qq, d); }
                if (l16 == 0) credv[w * 32 + rl] = make_float2(ss, qq);
            }
        __syncthreads();
        if (tid < 32) {
            float ss = 0.f, qq = 0.f;
#pragma unroll
            for (int ww = 0; ww < 4; ++ww) { float2 t = credv[ww * 32 + tid]; ss += t.x; qq += t.y; }
            float mu = ss * (1.f / 256.f);
            float var = qq * (1.f / 256.f) - mu * mu;
            cmu[tid] = mu;
            crs[tid] = 1.f / sqrtf(var + 1e-5f);
        }
        __syncthreads();
#pragma unroll
        for (int mt = 0; mt < 2; ++mt)
#pragma unroll
            for (int r = 0; r < 4; ++r) {
                int rl = mt * 16 + quad * 4 + r;
                float mu = cmu[rl], rs = crs[rl], we = wl[rl * 4 + e];
#pragma unroll
                for (int nt = 0; nt < 4; ++nt) {
                    float y = (acc[mt][nt][r] - mu) * rs * egv[nt] + ebv[nt];
                    oacc[mt][nt][r] += we * y;
                }
            }
        __syncthreads();   // all waves done with cmu/crs before next-e staging
    }
#pragma unroll
    for (int mt = 0; mt < 2; ++mt)
#pragma unroll
        for (int r = 0; r < 4; ++r) {
            int rl = mt * 16 + quad * 4 + r;
#pragma unroll
            for (int nt = 0; nt < 4; ++nt) {
                int col = w * 64 + nt * 16 + l16;
                outp[(size_t)(m0 + rl) * 256 + col] = oacc[mt][nt][r];
            }
        }
}

// ---------------------------------------------------------------------------
extern "C" void kernel_launch(void* const* d_in, const int* in_sizes, int n_in,
                              void* d_out, int out_size, void* d_ws, size_t ws_size,
                              hipStream_t stream) {
    const float* vis   = (const float*)d_in[0];
    const float* lang  = (const float*)d_in[1];
    const float* state = (const float*)d_in[2];
    const float* Wf    = (const float*)d_in[3];
    const float* bf_   = (const float*)d_in[4];
    const float* gf    = (const float*)d_in[5];
    const float* bfln  = (const float*)d_in[6];
    const float* Wg    = (const float*)d_in[7];
    const float* W1    = (const float*)d_in[8];
    const float* b1    = (const float*)d_in[9];
    const float* W2    = (const float*)d_in[10];
    const float* b2    = (const float*)d_in[11];
    const float* W3    = (const float*)d_in[12];
    const float* b3    = (const float*)d_in[13];
    const float* eg    = (const float*)d_in[14];
    const float* eb    = (const float*)d_in[15];
    float* outp = (float*)d_out;

    char* ws = (char*)d_ws;
    size_t off = 0;
    float* lbacc = (float*)(ws + off); off += 256;
    u16* WFT  = (u16*)(ws + off); off += 819200UL;     // WfT [256][1600]
    u16* W1T  = (u16*)(ws + off); off += 1048576UL;    // [E][512][256]
    u16* W2T  = (u16*)(ws + off); off += 1048576UL;    // [E][256][512]
    u16* W3T  = (u16*)(ws + off); off += 524288UL;     // [E][256][256]
    u16* XBF  = (u16*)(ws + off); off += 8388608UL;    // x bf16 [B][256]
    float* WR = (float*)(ws + off); off += 262144UL;   // gate weights [B][4]
    u16* H1   = (u16*)(ws + off); off += 67108864UL;   // [E][B][512]
    u16* H2   = (u16*)(ws + off); off += 33554432UL;   // [E][B][256]
    if (ws_size < off) return;

    int prep_blocks = (PREP_ITEMS + 255) / 256;
    prep_kernel<<<prep_blocks, 256, 0, stream>>>(Wf, W1, W2, W3, WFT, W1T, W2T, W3T, lbacc);
    fusion_kernel<<<512, 256, 0, stream>>>(vis, lang, state, WFT, bf_, gf, bfln, Wg,
                                           XBF, WR, lbacc);
    expert_kernel<8, 9><<<dim3(256, 2, 4), 256, 0, stream>>>(
        XBF, 256, 0L, W1T, 256, 131072L, b1, 512, H1, 512, 8388608L);
    expert_kernel<16, 18><<<dim3(256, 1, 4), 256, 0, stream>>>(
        H1, 512, 8388608L, W2T, 512, 131072L, b2, 256, H2, 256, 4194304L);
    combine_kernel<<<512, 256, 0, stream>>>(H2, W3T, b3, eg, eb, XBF, WR, lbacc, outp);
}